// Round 6
// baseline (491.530 us; speedup 1.0000x reference)
//
#include <hip/hip_runtime.h>
#include <math.h>

#define B_ROWS   1024
#define IN_FEAT  76800
#define OUT_FEAT 10
#define NF4      (IN_FEAT / 4)        // 19200 float4 per row
#define W_ELEMS  (OUT_FEAT * IN_FEAT) // 768000
#define EPSQ     1e-5f
// fused kernel: 1024 threads, 19 float4/thread; 19200 = 1024*18 + 768
#define NREG     19
#define TAILF4   768

// ---------------- K1: per-block partial sums of |W| ----------------
__global__ __launch_bounds__(256) void k_wabs_partial(const float* __restrict__ W,
                                                      float* __restrict__ partials) {
    const int tid = threadIdx.x, bid = blockIdx.x;
    float s = 0.f;
    for (int i = bid * 256 + tid; i < W_ELEMS; i += 256 * 256) s += fabsf(W[i]);
    #pragma unroll
    for (int off = 32; off >= 1; off >>= 1) s += __shfl_down(s, off, 64);
    __shared__ float red[4];
    const int wv = tid >> 6, ln = tid & 63;
    if (ln == 0) red[wv] = s;
    __syncthreads();
    if (tid == 0) partials[bid] = red[0] + red[1] + red[2] + red[3];
}

// ---------------- K2: final reduce -> scale_w = 1/clip(mean|W|, eps) ----------------
__global__ __launch_bounds__(256) void k_wscale(const float* __restrict__ partials,
                                                float* __restrict__ scale_w) {
    const int tid = threadIdx.x;
    float s = partials[tid];
    #pragma unroll
    for (int off = 32; off >= 1; off >>= 1) s += __shfl_down(s, off, 64);
    __shared__ float red[4];
    const int wv = tid >> 6, ln = tid & 63;
    if (ln == 0) red[wv] = s;
    __syncthreads();
    if (tid == 0) {
        float mean = (red[0] + red[1] + red[2] + red[3]) / (float)W_ELEMS;
        scale_w[0] = 1.0f / fmaxf(mean, EPSQ);
    }
}

// ---------------- K3: ternary-quantize + pack weights, 2 bits/output ----------------
// wpack[k] bits [2o+1:2o] = (code+1) in {0,1,2}. 307 KB total -> L2-resident during
// the fused GEMV; per-block re-reads are served at L2/L3 bandwidth (~10 us aggregate).
__global__ __launch_bounds__(256) void k_wpack(const float* __restrict__ W,
                                               const float* __restrict__ scale_w,
                                               unsigned int* __restrict__ wpack) {
    const int k = blockIdx.x * 256 + threadIdx.x;
    if (k >= IN_FEAT) return;
    const float s = scale_w[0];
    unsigned int u = 0;
    #pragma unroll
    for (int o = 0; o < OUT_FEAT; ++o) {
        float c = fminf(1.f, fmaxf(-1.f, rintf(W[o * IN_FEAT + k] * s)));
        u |= (unsigned int)((int)c + 1) << (2 * o);
    }
    wpack[k] = u;
}

// ---------------- K4: fully-fused absmax + quantize + GEMV + softmax ----------------
// x is read from HBM EXACTLY ONCE, held in registers across the absmax barrier.
// 1024 threads -> 19 float4/thread = 76 data VGPRs; total ~110 VGPR, under the
// 128-VGPR launchability cap for a 1024-thread block (one block/CU, 4 waves/EU).
// (R1/R2 spilled because the compiler was held to a 64-VGPR / 2-blocks-per-CU target.)
__device__ __forceinline__ void proc1(float xv, unsigned int w, float sx,
                                      float* acc, float& sq) {
    float q = rintf(xv * sx);   // |x*sx| <= 127 -> rint in [-127,127], no clamp needed
    sq += q;
    #pragma unroll
    for (int o = 0; o < OUT_FEAT; ++o)
        acc[o] = fmaf(q, (float)((w >> (2 * o)) & 3u), acc[o]);
}

__device__ __forceinline__ void proc4(float4 v, uint4 w, float sx, float* acc, float& sq) {
    proc1(v.x, w.x, sx, acc, sq);
    proc1(v.y, w.y, sx, acc, sq);
    proc1(v.z, w.z, sx, acc, sq);
    proc1(v.w, w.w, sx, acc, sq);
}

__global__ __launch_bounds__(1024, 1) void k_fused(const float* __restrict__ x,
                                                   const unsigned int* __restrict__ wpack,
                                                   const float* __restrict__ bias,
                                                   const float* __restrict__ scale_w,
                                                   float* __restrict__ out) {
    __shared__ float redmax[16];
    __shared__ float racc[16][12];
    __shared__ float fin[12];
    __shared__ float lgs[OUT_FEAT];

    const int tid = threadIdx.x;
    const int row = blockIdx.x;
    const float sw = scale_w[0];
    const float4* __restrict__ xr = (const float4*)(x + (size_t)row * IN_FEAT);

    // ---- phase 1: load entire row into registers, tracking absmax ----
    float4 xc[NREG];
    float m = 0.f;
    #pragma unroll
    for (int j = 0; j < NREG - 1; ++j) {       // 18 full strides of 1024
        xc[j] = xr[tid + j * 1024];
        m = fmaxf(m, fmaxf(fmaxf(fabsf(xc[j].x), fabsf(xc[j].y)),
                           fmaxf(fabsf(xc[j].z), fabsf(xc[j].w))));
    }
    if (tid < TAILF4) {                        // tail: 768 float4
        xc[NREG - 1] = xr[(NREG - 1) * 1024 + tid];
        m = fmaxf(m, fmaxf(fmaxf(fabsf(xc[NREG - 1].x), fabsf(xc[NREG - 1].y)),
                           fmaxf(fabsf(xc[NREG - 1].z), fabsf(xc[NREG - 1].w))));
    }

    // ---- absmax block reduce -> sx (each thread computes it: one barrier only) ----
    #pragma unroll
    for (int off = 32; off >= 1; off >>= 1) m = fmaxf(m, __shfl_down(m, off, 64));
    const int wv = tid >> 6, ln = tid & 63;
    if (ln == 0) redmax[wv] = m;
    __syncthreads();
    float mm = redmax[0];
    #pragma unroll
    for (int i = 1; i < 16; ++i) mm = fmaxf(mm, redmax[i]);
    const float sx = 127.0f / fmaxf(mm, EPSQ);

    // ---- phase 2: quantize from REGISTERS + GEMV (weights stream from L2) ----
    float acc[OUT_FEAT] = {0.f,0.f,0.f,0.f,0.f,0.f,0.f,0.f,0.f,0.f};
    float sq = 0.f;
    const uint4* __restrict__ wp4 = (const uint4*)wpack;
    #pragma unroll
    for (int j = 0; j < NREG - 1; ++j) {
        uint4 w = wp4[tid + j * 1024];
        proc4(xc[j], w, sx, acc, sq);
    }
    if (tid < TAILF4) {
        uint4 w = wp4[(NREG - 1) * 1024 + tid];
        proc4(xc[NREG - 1], w, sx, acc, sq);
    }

    // ---- phase 3: block reduce 11 values (10 accs + sum_q) across 16 waves ----
    float vals[11];
    #pragma unroll
    for (int t = 0; t < OUT_FEAT; ++t) vals[t] = acc[t];
    vals[10] = sq;
    #pragma unroll
    for (int t = 0; t < 11; ++t) {
        #pragma unroll
        for (int off = 32; off >= 1; off >>= 1) vals[t] += __shfl_down(vals[t], off, 64);
    }
    if (ln == 0) {
        #pragma unroll
        for (int t = 0; t < 11; ++t) racc[wv][t] = vals[t];
    }
    __syncthreads();
    if (tid < 11) {
        float s = 0.f;
        #pragma unroll
        for (int w2 = 0; w2 < 16; ++w2) s += racc[w2][tid];
        fin[tid] = s;
    }
    __syncthreads();
    if (tid < OUT_FEAT) {
        // sum q*(c+1) - sum q = sum q*c ; dequant by 1/(sx*sw)
        float inv = 1.0f / (sx * sw);
        lgs[tid] = (fin[tid] - fin[10]) * inv + bias[tid];
    }
    __syncthreads();
    if (tid < OUT_FEAT) {
        float mx = lgs[0];
        #pragma unroll
        for (int o = 1; o < OUT_FEAT; ++o) mx = fmaxf(mx, lgs[o]);
        float den = 0.f;
        #pragma unroll
        for (int o = 0; o < OUT_FEAT; ++o) den += __expf(lgs[o] - mx);
        float e = __expf(lgs[tid] - mx);
        out[row * OUT_FEAT + tid] = e / den;
    }
}

extern "C" void kernel_launch(void* const* d_in, const int* in_sizes, int n_in,
                              void* d_out, int out_size, void* d_ws, size_t ws_size,
                              hipStream_t stream) {
    const float* x    = (const float*)d_in[0];
    const float* Wmat = (const float*)d_in[1];
    const float* bias = (const float*)d_in[2];
    float* out = (float*)d_out;

    char* wsb = (char*)d_ws;
    float* scale_w      = (float*)wsb;                    // 1 float
    float* partials     = (float*)(wsb + 256);            // 256 floats
    unsigned int* wpack = (unsigned int*)(wsb + 4096);    // 76800 uint32 = 307 KB

    k_wabs_partial<<<256, 256, 0, stream>>>(Wmat, partials);
    k_wscale<<<1, 256, 0, stream>>>(partials, scale_w);
    k_wpack<<<(IN_FEAT + 255) / 256, 256, 0, stream>>>(Wmat, scale_w, wpack);
    k_fused<<<B_ROWS, 1024, 0, stream>>>(x, wpack, bias, scale_w, out);
}

// Round 7
// 459.522 us; speedup vs baseline: 1.0697x; 1.0697x over previous
//
#include <hip/hip_runtime.h>
#include <math.h>

#define B_ROWS   1024
#define IN_FEAT  76800
#define OUT_FEAT 10
#define NF4      (IN_FEAT / 4)        // 19200 float4 (= i8-quad groups) per row
#define W_ELEMS  (OUT_FEAT * IN_FEAT) // 768000
#define EPSQ     1e-5f
// fused kernel: 1024 threads; row = 19200 float4 = 8 LDS strides + 10 reg strides + 768 tail
#define NLDSJ    8                    // strides cached in LDS (8*1024 float4 = 128 KB)
#define NREGJ    10                   // full register strides (j = 8..17)
#define TAILF4   768                  // partial stride j = 18

#if __has_builtin(__builtin_amdgcn_sdot4)
#define SDOT4(a, b, c) __builtin_amdgcn_sdot4((int)(a), (int)(b), (c), false)
#else
__device__ __forceinline__ int sdot4_sw(unsigned a, unsigned b, int c) {
    #pragma unroll
    for (int i = 0; i < 4; ++i)
        c += (int)(signed char)(a >> (8 * i)) * (int)(signed char)(b >> (8 * i));
    return c;
}
#define SDOT4(a, b, c) sdot4_sw((a), (b), (c))
#endif

// ---------------- K1: per-block partial sums of |W| ----------------
__global__ __launch_bounds__(256) void k_wabs_partial(const float* __restrict__ W,
                                                      float* __restrict__ partials) {
    const int tid = threadIdx.x, bid = blockIdx.x;
    float s = 0.f;
    for (int i = bid * 256 + tid; i < W_ELEMS; i += 256 * 256) s += fabsf(W[i]);
    #pragma unroll
    for (int off = 32; off >= 1; off >>= 1) s += __shfl_down(s, off, 64);
    __shared__ float red[4];
    const int wv = tid >> 6, ln = tid & 63;
    if (ln == 0) red[wv] = s;
    __syncthreads();
    if (tid == 0) partials[bid] = red[0] + red[1] + red[2] + red[3];
}

// ---------------- K2: final reduce -> scale_w = 1/clip(mean|W|, eps) ----------------
__global__ __launch_bounds__(256) void k_wscale(const float* __restrict__ partials,
                                                float* __restrict__ scale_w) {
    const int tid = threadIdx.x;
    float s = partials[tid];
    #pragma unroll
    for (int off = 32; off >= 1; off >>= 1) s += __shfl_down(s, off, 64);
    __shared__ float red[4];
    const int wv = tid >> 6, ln = tid & 63;
    if (ln == 0) red[wv] = s;
    __syncthreads();
    if (tid == 0) {
        float mean = (red[0] + red[1] + red[2] + red[3]) / (float)W_ELEMS;
        scale_w[0] = 1.0f / fmaxf(mean, EPSQ);
    }
}

// ---------------- K3: ternary-quantize weights into SIGNED i8 quad planes ----------------
// For group g (elements 4g..4g+3): wa[g] = outputs 0..3, wb[g] = outputs 4..7,
// wc[g] = outputs 8..9; each u32 holds 4 signed-i8 codes in {-1,0,1}.
// One uint4+uint4+uint2 load per group serves all 10 outputs (v_dot4_i32_i8 operands).
__global__ __launch_bounds__(256) void k_wpackdot(const float* __restrict__ W,
                                                  const float* __restrict__ scale_w,
                                                  uint4* __restrict__ wa,
                                                  uint4* __restrict__ wb,
                                                  uint2* __restrict__ wc) {
    const int g = blockIdx.x * 256 + threadIdx.x;
    if (g >= NF4) return;
    const float s = scale_w[0];
    unsigned pk[OUT_FEAT];
    #pragma unroll
    for (int o = 0; o < OUT_FEAT; ++o) {
        const float4 wv = *(const float4*)(W + (size_t)o * IN_FEAT + 4 * g);
        int c0 = (int)fminf(1.f, fmaxf(-1.f, rintf(wv.x * s)));
        int c1 = (int)fminf(1.f, fmaxf(-1.f, rintf(wv.y * s)));
        int c2 = (int)fminf(1.f, fmaxf(-1.f, rintf(wv.z * s)));
        int c3 = (int)fminf(1.f, fmaxf(-1.f, rintf(wv.w * s)));
        pk[o] = (unsigned)(c0 & 255) | ((unsigned)(c1 & 255) << 8) |
                ((unsigned)(c2 & 255) << 16) | ((unsigned)(c3 & 255) << 24);
    }
    wa[g] = make_uint4(pk[0], pk[1], pk[2], pk[3]);
    wb[g] = make_uint4(pk[4], pk[5], pk[6], pk[7]);
    wc[g] = make_uint2(pk[8], pk[9]);
}

// ---------------- K4: fused absmax + i8 quantize + dot4 GEMV + softmax ----------------
// x read from HBM exactly once; first 128 KB of the row parked in LDS (each thread
// re-reads only its own slots -> conflict-free ds_read_b128), the rest (11 float4 =
// 44 VGPR) in registers. Peak pressure ~90-100 VGPR, safely under the 128 cap.
// Inner loop: 10 v_dot4_i32_i8 per 4 elements (signed codes -> no sum_q correction).
__device__ __forceinline__ void dot4g(float4 v, float sx,
                                      const uint4* __restrict__ wa,
                                      const uint4* __restrict__ wb,
                                      const uint2* __restrict__ wc,
                                      int idx, int* acc) {
    int q0 = (int)rintf(v.x * sx);    // |x*sx| <= 127 -> fits i8, no clamp needed
    int q1 = (int)rintf(v.y * sx);
    int q2 = (int)rintf(v.z * sx);
    int q3 = (int)rintf(v.w * sx);
    unsigned qp = (unsigned)(q0 & 255) | ((unsigned)(q1 & 255) << 8) |
                  ((unsigned)(q2 & 255) << 16) | ((unsigned)(q3 & 255) << 24);
    uint4 a = wa[idx];
    uint4 b = wb[idx];
    uint2 c2 = wc[idx];
    acc[0] = SDOT4(qp, a.x, acc[0]);
    acc[1] = SDOT4(qp, a.y, acc[1]);
    acc[2] = SDOT4(qp, a.z, acc[2]);
    acc[3] = SDOT4(qp, a.w, acc[3]);
    acc[4] = SDOT4(qp, b.x, acc[4]);
    acc[5] = SDOT4(qp, b.y, acc[5]);
    acc[6] = SDOT4(qp, b.z, acc[6]);
    acc[7] = SDOT4(qp, b.w, acc[7]);
    acc[8] = SDOT4(qp, c2.x, acc[8]);
    acc[9] = SDOT4(qp, c2.y, acc[9]);
}

__global__ __launch_bounds__(1024, 1) void k_fused(const float* __restrict__ x,
                                                   const uint4* __restrict__ wa,
                                                   const uint4* __restrict__ wb,
                                                   const uint2* __restrict__ wc,
                                                   const float* __restrict__ bias,
                                                   const float* __restrict__ scale_w,
                                                   float* __restrict__ out) {
    __shared__ float4 xlds[NLDSJ * 1024];    // 128 KB
    __shared__ float  redmax[16];
    __shared__ int    racc[16][OUT_FEAT];
    __shared__ int    fin[OUT_FEAT];
    __shared__ float  lgs[OUT_FEAT];

    const int tid = threadIdx.x;
    const int row = blockIdx.x;
    const float sw = scale_w[0];
    const float4* __restrict__ xr = (const float4*)(x + (size_t)row * IN_FEAT);

    // ---- phase 1: single global read; LDS for strides 0..7, regs for 8..18 ----
    float4 xc[NREGJ + 1];
    float m = 0.f;
    #pragma unroll
    for (int j = 0; j < NLDSJ; ++j) {
        float4 v = xr[tid + j * 1024];
        xlds[tid + j * 1024] = v;
        m = fmaxf(m, fmaxf(fmaxf(fabsf(v.x), fabsf(v.y)), fmaxf(fabsf(v.z), fabsf(v.w))));
    }
    #pragma unroll
    for (int j = 0; j < NREGJ; ++j) {
        xc[j] = xr[tid + (NLDSJ + j) * 1024];
        m = fmaxf(m, fmaxf(fmaxf(fabsf(xc[j].x), fabsf(xc[j].y)),
                           fmaxf(fabsf(xc[j].z), fabsf(xc[j].w))));
    }
    if (tid < TAILF4) {
        xc[NREGJ] = xr[(NLDSJ + NREGJ) * 1024 + tid];
        m = fmaxf(m, fmaxf(fmaxf(fabsf(xc[NREGJ].x), fabsf(xc[NREGJ].y)),
                           fmaxf(fabsf(xc[NREGJ].z), fabsf(xc[NREGJ].w))));
    }

    // ---- absmax block reduce -> sx ----
    #pragma unroll
    for (int off = 32; off >= 1; off >>= 1) m = fmaxf(m, __shfl_down(m, off, 64));
    const int wv = tid >> 6, ln = tid & 63;
    if (ln == 0) redmax[wv] = m;
    __syncthreads();
    float mm = redmax[0];
    #pragma unroll
    for (int i = 1; i < 16; ++i) mm = fmaxf(mm, redmax[i]);
    const float sx = 127.0f / fmaxf(mm, EPSQ);

    // ---- phase 2: quantize (LDS + regs) + dot4 GEMV, exact int accumulate ----
    int acc[OUT_FEAT] = {0, 0, 0, 0, 0, 0, 0, 0, 0, 0};
    #pragma unroll
    for (int j = 0; j < NLDSJ; ++j) {
        const int idx = tid + j * 1024;
        dot4g(xlds[idx], sx, wa, wb, wc, idx, acc);
    }
    #pragma unroll
    for (int j = 0; j < NREGJ; ++j) {
        const int idx = tid + (NLDSJ + j) * 1024;
        dot4g(xc[j], sx, wa, wb, wc, idx, acc);
    }
    if (tid < TAILF4) {
        const int idx = (NLDSJ + NREGJ) * 1024 + tid;
        dot4g(xc[NREGJ], sx, wa, wb, wc, idx, acc);
    }

    // ---- phase 3: block reduce 10 int accumulators across 16 waves ----
    #pragma unroll
    for (int t = 0; t < OUT_FEAT; ++t) {
        #pragma unroll
        for (int off = 32; off >= 1; off >>= 1) acc[t] += __shfl_down(acc[t], off, 64);
    }
    if (ln == 0) {
        #pragma unroll
        for (int t = 0; t < OUT_FEAT; ++t) racc[wv][t] = acc[t];
    }
    __syncthreads();
    if (tid < OUT_FEAT) {
        int s = 0;
        #pragma unroll
        for (int w2 = 0; w2 < 16; ++w2) s += racc[w2][tid];
        fin[tid] = s;
    }
    __syncthreads();
    if (tid < OUT_FEAT) {
        const float inv = 1.0f / (sx * sw);   // dequant: sum q*c / (sx*sw)
        lgs[tid] = (float)fin[tid] * inv + bias[tid];
    }
    __syncthreads();
    if (tid < OUT_FEAT) {
        float mx = lgs[0];
        #pragma unroll
        for (int o = 1; o < OUT_FEAT; ++o) mx = fmaxf(mx, lgs[o]);
        float den = 0.f;
        #pragma unroll
        for (int o = 0; o < OUT_FEAT; ++o) den += __expf(lgs[o] - mx);
        float e = __expf(lgs[tid] - mx);
        out[row * OUT_FEAT + tid] = e / den;
    }
}

extern "C" void kernel_launch(void* const* d_in, const int* in_sizes, int n_in,
                              void* d_out, int out_size, void* d_ws, size_t ws_size,
                              hipStream_t stream) {
    const float* x    = (const float*)d_in[0];
    const float* Wmat = (const float*)d_in[1];
    const float* bias = (const float*)d_in[2];
    float* out = (float*)d_out;

    char* wsb = (char*)d_ws;
    float* scale_w  = (float*)wsb;                       // 1 float
    float* partials = (float*)(wsb + 256);               // 256 floats
    uint4* wa       = (uint4*)(wsb + 4096);              // 19200 uint4 = 307200 B
    uint4* wb       = (uint4*)(wsb + 4096 + 307200);     // 307200 B
    uint2* wc       = (uint2*)(wsb + 4096 + 614400);     // 153600 B  (total ~772 KB)

    k_wabs_partial<<<256, 256, 0, stream>>>(Wmat, partials);
    k_wscale<<<1, 256, 0, stream>>>(partials, scale_w);
    k_wpackdot<<<(NF4 + 255) / 256, 256, 0, stream>>>(Wmat, scale_w, wa, wb, wc);
    k_fused<<<B_ROWS, 1024, 0, stream>>>(x, wa, wb, wc, bias, scale_w, out);
}